// Round 1
// baseline (190.374 us; speedup 1.0000x reference)
//
#include <hip/hip_runtime.h>

#define N_CLASSES 100
#define ROWS_PER_TILE 64
#define BLOCK 256
#define F4_PER_TILE (ROWS_PER_TILE * N_CLASSES / 4) /* 1600 */
#define EPS 1e-7f

__global__ __launch_bounds__(BLOCK) void sens_count_kernel(
    const float* __restrict__ y_pred, const int* __restrict__ y_true,
    unsigned int* __restrict__ counters, int n_rows)
{
    __shared__ float s_rows[ROWS_PER_TILE * N_CLASSES];
    __shared__ unsigned int s_pc[N_CLASSES];
    __shared__ unsigned int s_tp[N_CLASSES];

    const int tid = threadIdx.x;
    for (int i = tid; i < N_CLASSES; i += BLOCK) { s_pc[i] = 0u; s_tp[i] = 0u; }

    const int n_tiles = (n_rows + ROWS_PER_TILE - 1) / ROWS_PER_TILE;
    const long long total_f4 = (long long)n_rows * (N_CLASSES / 4);

    for (int tile = blockIdx.x; tile < n_tiles; tile += gridDim.x) {
        const long long row0 = (long long)tile * ROWS_PER_TILE;
        __syncthreads();  // s_rows from previous tile fully consumed

        // ---- stage 64 rows (1600 float4 = 25.6 KB) fully coalesced ----
        const float4* __restrict__ src =
            (const float4*)(y_pred + row0 * N_CLASSES);
        float4* dst = (float4*)s_rows;
        const long long base_f4 = row0 * (N_CLASSES / 4);
        const int tile_f4 = (int)((total_f4 - base_f4) < F4_PER_TILE
                                      ? (total_f4 - base_f4) : F4_PER_TILE);
        for (int i = tid; i < tile_f4; i += BLOCK) dst[i] = src[i];
        __syncthreads();

        // ---- argmax: 4 threads per row, 25 elements each ----
        const int r = tid >> 2;   // row within tile, 0..63
        const int q = tid & 3;    // quarter, 0..3
        const long long grow = row0 + r;
        if (grow < n_rows) {
            const float* rowp = &s_rows[r * N_CLASSES + q * 25];
            float best = rowp[0];
            int bidx = q * 25;
            #pragma unroll
            for (int t = 1; t < 25; ++t) {
                float v = rowp[t];
                if (v > best) { best = v; bidx = q * 25 + t; }  // strict >: first max wins
            }
            // combine across the quad; on equal value prefer lower index (jnp argmax)
            #pragma unroll
            for (int m = 1; m <= 2; m <<= 1) {
                float ov = __shfl_xor(best, m, 64);
                int   oi = __shfl_xor(bidx, m, 64);
                if (ov > best || (ov == best && oi < bidx)) { best = ov; bidx = oi; }
            }
            if (q == 0) {
                atomicAdd(&s_pc[bidx], 1u);
                if (y_true[grow] == bidx) atomicAdd(&s_tp[bidx], 1u);
            }
        }
    }

    __syncthreads();
    for (int i = tid; i < N_CLASSES; i += BLOCK) {
        unsigned int pc = s_pc[i], tp = s_tp[i];
        if (pc) atomicAdd(&counters[i], pc);
        if (tp) atomicAdd(&counters[N_CLASSES + i], tp);
    }
}

__global__ void sens_final_kernel(const unsigned int* __restrict__ counters,
                                  float* __restrict__ out)
{
    const int lane = threadIdx.x;  // one wave of 64
    float acc = 0.f;
    for (int c = lane; c < N_CLASSES; c += 64) {
        float pc = (float)counters[c];
        float tp = (float)counters[N_CLASSES + c];
        acc += tp / (pc + EPS);
    }
    #pragma unroll
    for (int m = 32; m >= 1; m >>= 1) acc += __shfl_xor(acc, m, 64);
    if (lane == 0) out[0] = acc / (float)N_CLASSES;
}

extern "C" void kernel_launch(void* const* d_in, const int* in_sizes, int n_in,
                              void* d_out, int out_size, void* d_ws, size_t ws_size,
                              hipStream_t stream)
{
    const float* y_pred = (const float*)d_in[0];
    const int*   y_true = (const int*)d_in[1];
    float* out = (float*)d_out;
    const int n_rows = in_sizes[1];  // 2,000,000

    unsigned int* counters = (unsigned int*)d_ws;  // [pc: 100][tp: 100]
    hipMemsetAsync(counters, 0, 2 * N_CLASSES * sizeof(unsigned int), stream);

    const int grid = 1024;  // grid-stride; keeps global atomic flush cheap
    sens_count_kernel<<<grid, BLOCK, 0, stream>>>(y_pred, y_true, counters, n_rows);
    sens_final_kernel<<<1, 64, 0, stream>>>(counters, out);
}

// Round 2
// 165.509 us; speedup vs baseline: 1.1502x; 1.1502x over previous
//
#include <hip/hip_runtime.h>
#include <stdint.h>

#define N_CLASSES 100
#define ROWS_PER_TILE 64
#define BLOCK 320                    // 5 waves of 64
#define F4_PER_TILE 1600             // 64*100/4 float4 per tile
#define LOADS_PER_THREAD 5           // 1600/320 -> uniform per wave -> vmcnt(5)
#define EPS 1e-7f

__device__ __forceinline__ void lds_dma16(void* lds, const void* g) {
    __builtin_amdgcn_global_load_lds(
        (const __attribute__((address_space(1))) uint32_t*)g,
        (__attribute__((address_space(3))) uint32_t*)lds, 16, 0, 0);
}

__global__ __launch_bounds__(BLOCK) void sens_count_kernel(
    const float* __restrict__ y_pred, const int* __restrict__ y_true,
    unsigned int* __restrict__ counters, int n_rows)
{
    __shared__ float s_rows[2][ROWS_PER_TILE * N_CLASSES];  // 2 x 25.6 KB
    __shared__ unsigned int s_pc[N_CLASSES];
    __shared__ unsigned int s_tp[N_CLASSES];

    const int tid = threadIdx.x;
    for (int i = tid; i < N_CLASSES; i += BLOCK) { s_pc[i] = 0u; s_tp[i] = 0u; }
    __syncthreads();   // zero-init drained before any histogram atomics

    const long long n_tiles = ((long long)n_rows + ROWS_PER_TILE - 1) / ROWS_PER_TILE;
    const long long total_f4 = (long long)n_rows * (N_CLASSES / 4);

    // Issue all DMA loads for tile t into buffer b. Linear layout: per-lane
    // LDS dst = wave-uniform base + lane*16 (the global_load_lds contract).
    auto issue_tile = [&](long long t, int b) {
        const long long base_f4 = t * (long long)F4_PER_TILE;
        float* dst = s_rows[b];
        #pragma unroll
        for (int k = 0; k < LOADS_PER_THREAD; ++k) {
            const int i = k * BLOCK + tid;
            long long gi = base_f4 + i;
            if (gi >= total_f4) gi = total_f4 - 1;  // clamp src: keeps issue count uniform
            lds_dma16(dst + (size_t)i * 4, y_pred + gi * 4);
        }
    };

    long long tile = blockIdx.x;
    int cur = 0;
    if (tile < n_tiles) issue_tile(tile, 0);   // prologue: tile 0 in flight

    for (; tile < n_tiles; tile += gridDim.x) {
        const int r = tid >> 2;          // row in tile (threads 0..255 compute)
        const int q = tid & 3;           // quarter of row
        const long long grow = tile * ROWS_PER_TILE + r;

        // Prefetch y_true BEFORE issuing next tile's DMA so its auto-waitcnt
        // is vmcnt(5), not a pipeline-draining vmcnt(0).
        int tv = -1;
        if (tid < 256 && grow < n_rows) tv = y_true[grow];

        const long long next = tile + gridDim.x;
        if (next < n_tiles) {
            issue_tile(next, cur ^ 1);
            asm volatile("s_waitcnt vmcnt(5)" ::: "memory");  // current tile landed
        } else {
            asm volatile("s_waitcnt vmcnt(0)" ::: "memory");  // epilogue drain
        }
        asm volatile("s_barrier" ::: "memory");   // B1: tile visible to all waves

        if (tid < 256 && grow < n_rows) {
            const float* rowp = &s_rows[cur][r * N_CLASSES + q * 25];
            float best = rowp[0];
            int bidx = q * 25;
            #pragma unroll
            for (int t2 = 1; t2 < 25; ++t2) {
                float v = rowp[t2];
                if (v > best) { best = v; bidx = q * 25 + t2; }  // strict >: first max
            }
            #pragma unroll
            for (int m = 1; m <= 2; m <<= 1) {
                float ov = __shfl_xor(best, m, 64);
                int   oi = __shfl_xor(bidx, m, 64);
                if (ov > best || (ov == best && oi < bidx)) { best = ov; bidx = oi; }
            }
            if (q == 0) {
                atomicAdd(&s_pc[bidx], 1u);
                if (tv == bidx) atomicAdd(&s_tp[bidx], 1u);
            }
        }
        asm volatile("s_barrier" ::: "memory");   // B2: done reading s_rows[cur]
        cur ^= 1;
    }

    __syncthreads();   // drain LDS atomics before flush
    for (int i = tid; i < N_CLASSES; i += BLOCK) {
        unsigned int pc = s_pc[i], tp = s_tp[i];
        if (pc) atomicAdd(&counters[i], pc);
        if (tp) atomicAdd(&counters[N_CLASSES + i], tp);
    }
}

__global__ void sens_final_kernel(const unsigned int* __restrict__ counters,
                                  float* __restrict__ out)
{
    const int lane = threadIdx.x;  // one wave of 64
    float acc = 0.f;
    for (int c = lane; c < N_CLASSES; c += 64) {
        float pc = (float)counters[c];
        float tp = (float)counters[N_CLASSES + c];
        acc += tp / (pc + EPS);
    }
    #pragma unroll
    for (int m = 32; m >= 1; m >>= 1) acc += __shfl_xor(acc, m, 64);
    if (lane == 0) out[0] = acc / (float)N_CLASSES;
}

extern "C" void kernel_launch(void* const* d_in, const int* in_sizes, int n_in,
                              void* d_out, int out_size, void* d_ws, size_t ws_size,
                              hipStream_t stream)
{
    const float* y_pred = (const float*)d_in[0];
    const int*   y_true = (const int*)d_in[1];
    float* out = (float*)d_out;
    const int n_rows = in_sizes[1];  // 2,000,000

    unsigned int* counters = (unsigned int*)d_ws;  // [pc: 100][tp: 100]
    hipMemsetAsync(counters, 0, 2 * N_CLASSES * sizeof(unsigned int), stream);

    long long n_tiles = ((long long)n_rows + ROWS_PER_TILE - 1) / ROWS_PER_TILE;
    int grid = 768;                      // 3 blocks/CU (LDS-limited), grid-stride
    if (n_tiles < grid) grid = (int)n_tiles;

    sens_count_kernel<<<grid, BLOCK, 0, stream>>>(y_pred, y_true, counters, n_rows);
    sens_final_kernel<<<1, 64, 0, stream>>>(counters, out);
}

// Round 3
// 148.639 us; speedup vs baseline: 1.2808x; 1.1135x over previous
//
#include <hip/hip_runtime.h>
#include <stdint.h>

#define N_CLASSES 100
#define ROWS_PER_WTILE 16
#define DW_PER_WTILE (ROWS_PER_WTILE * N_CLASSES)   /* 1600 dwords = 6.4 KB */
#define LOADS_PER_LANE (DW_PER_WTILE / 64)          /* 25 -> vmcnt(25) */
#define BLOCK 256
#define WAVES_PER_BLOCK (BLOCK / 64)
#define EPS 1e-7f

__device__ __forceinline__ void lds_dma4(void* lds, const void* g) {
    __builtin_amdgcn_global_load_lds(
        (const __attribute__((address_space(1))) uint32_t*)g,
        (__attribute__((address_space(3))) uint32_t*)lds, 4, 0, 0);
}

__global__ __launch_bounds__(BLOCK) void sens_count_kernel(
    const float* __restrict__ y_pred, const int* __restrict__ y_true,
    unsigned int* __restrict__ counters, int n_rows)
{
    // Wave-private double buffers: no s_barrier in the main loop.
    __shared__ float s_rows[WAVES_PER_BLOCK][2][DW_PER_WTILE];  // 4*2*6.4KB = 51.2KB
    __shared__ unsigned int s_pc[N_CLASSES];
    __shared__ unsigned int s_tp[N_CLASSES];

    const int tid  = threadIdx.x;
    const int wave = tid >> 6;
    const int lane = tid & 63;

    for (int i = tid; i < N_CLASSES; i += BLOCK) { s_pc[i] = 0u; s_tp[i] = 0u; }
    __syncthreads();   // hist zero-init visible before any atomics

    const long long n_wtiles = ((long long)n_rows + ROWS_PER_WTILE - 1) / ROWS_PER_WTILE;
    const long long total_dw = (long long)n_rows * N_CLASSES;
    const long long stride   = (long long)gridDim.x * WAVES_PER_BLOCK;

    // Issue one wave-tile via DMA. LDS dst = wave-uniform base + lane*4 (contract).
    auto issue = [&](long long t, int b) {
        const long long base = t * (long long)DW_PER_WTILE;
        float* dst = s_rows[wave][b];
        const float* gp = y_pred + base;
        if (base + DW_PER_WTILE <= total_dw) {      // full tile: no per-load clamp
            #pragma unroll
            for (int k = 0; k < LOADS_PER_LANE; ++k) {
                const int i = k * 64 + lane;
                lds_dma4(dst + i, gp + i);
            }
        } else {
            #pragma unroll
            for (int k = 0; k < LOADS_PER_LANE; ++k) {
                const int i = k * 64 + lane;
                long long gi = base + i;
                if (gi >= total_dw) gi = total_dw - 1;
                lds_dma4(dst + i, y_pred + gi);
            }
        }
    };

    long long t = (long long)blockIdx.x * WAVES_PER_BLOCK + wave;
    int cur = 0;
    if (t < n_wtiles) issue(t, 0);   // prologue: first tile in flight

    for (; t < n_wtiles; t += stride) {
        const int r = lane >> 2;     // row in wave-tile, 0..15
        const int q = lane & 3;      // quarter of row
        const long long grow = t * ROWS_PER_WTILE + r;

        // y_true prefetch BEFORE next-tile issue -> its auto-waitcnt is vmcnt(25).
        int tv = -1;
        if (grow < (long long)n_rows) tv = y_true[grow];

        const long long nxt = t + stride;
        if (nxt < n_wtiles) {
            issue(nxt, cur ^ 1);
            asm volatile("s_waitcnt vmcnt(25)" ::: "memory");  // current tile + tv landed
        } else {
            asm volatile("s_waitcnt vmcnt(0)" ::: "memory");   // epilogue drain
        }

        if (grow < (long long)n_rows) {
            const float* rowp = &s_rows[wave][cur][r * N_CLASSES + q * 25];
            float best = rowp[0];
            int bidx = q * 25;
            #pragma unroll
            for (int i2 = 1; i2 < 25; ++i2) {
                float v = rowp[i2];
                if (v > best) { best = v; bidx = q * 25 + i2; }  // strict >: first max
            }
            #pragma unroll
            for (int m = 1; m <= 2; m <<= 1) {
                float ov = __shfl_xor(best, m, 64);
                int   oi = __shfl_xor(bidx, m, 64);
                if (ov > best || (ov == best && oi < bidx)) { best = ov; bidx = oi; }
            }
            if (q == 0) {
                atomicAdd(&s_pc[bidx], 1u);
                if (tv == bidx) atomicAdd(&s_tp[bidx], 1u);
            }
        }
        cur ^= 1;
    }

    __syncthreads();   // all waves' LDS hist atomics done
    for (int i = tid; i < N_CLASSES; i += BLOCK) {
        unsigned int pc = s_pc[i], tp = s_tp[i];
        if (pc) atomicAdd(&counters[i], pc);
        if (tp) atomicAdd(&counters[N_CLASSES + i], tp);
    }
}

__global__ void sens_final_kernel(const unsigned int* __restrict__ counters,
                                  float* __restrict__ out)
{
    const int lane = threadIdx.x;  // one wave
    float acc = 0.f;
    for (int c = lane; c < N_CLASSES; c += 64) {
        float pc = (float)counters[c];
        float tp = (float)counters[N_CLASSES + c];
        acc += tp / (pc + EPS);
    }
    #pragma unroll
    for (int m = 32; m >= 1; m >>= 1) acc += __shfl_xor(acc, m, 64);
    if (lane == 0) out[0] = acc / (float)N_CLASSES;
}

extern "C" void kernel_launch(void* const* d_in, const int* in_sizes, int n_in,
                              void* d_out, int out_size, void* d_ws, size_t ws_size,
                              hipStream_t stream)
{
    const float* y_pred = (const float*)d_in[0];
    const int*   y_true = (const int*)d_in[1];
    float* out = (float*)d_out;
    const int n_rows = in_sizes[1];  // 2,000,000

    unsigned int* counters = (unsigned int*)d_ws;  // [pc:100][tp:100]
    hipMemsetAsync(counters, 0, 2 * N_CLASSES * sizeof(unsigned int), stream);

    const int grid = 768;  // 3 blocks/CU (52KB LDS each), 15 waves/CU streaming
    sens_count_kernel<<<grid, BLOCK, 0, stream>>>(y_pred, y_true, counters, n_rows);
    sens_final_kernel<<<1, 64, 0, stream>>>(counters, out);
}